// Round 4
// baseline (651.879 us; speedup 1.0000x reference)
//
#include <hip/hip_runtime.h>

// LAYER_IDX = [0, 4096, 6144, 7168, 7680, 7682]
// L1: 4096->2048 ebase 0       | L2: 2048->1024 ebase 262144
// L3: 1024->512  ebase 393216  | out: 512->2    ebase 458752
// v4: SINGLE persistent kernel, software grid barriers. Wave w owns L1 node w;
// per layer: gather (pre-normalized bf16 acts) -> stats shadow atomics ->
// grid barrier -> block-local stats fold -> normalize OWN row from regs ->
// write bf16 act -> barrier -> next layer. 256 blocks x 512 thr (2/CU safe).
#define FAN_IN 128
#define EPS 1e-5f
#define NSH 32            // stats shadow copies (atomic contention spread)
#define NBLK 256

typedef unsigned short u16;
typedef unsigned int u32;

__device__ __forceinline__ u16 f2bf(float f) {   // fp32->bf16 RNE
    union { float f; u32 u; } v; v.f = f;
    u32 r = v.u + 0x7fffu + ((v.u >> 16) & 1u);
    return (u16)(r >> 16);
}
__device__ __forceinline__ float bflo(u32 u) { return __uint_as_float(u << 16); }
__device__ __forceinline__ float bfhi(u32 u) { return __uint_as_float(u & 0xffff0000u); }

// ---------------------------------------------------------------------------
// prep: transpose x[512][4096] f32 -> xT[4096][512] bf16 (blocks 0..511);
// blocks 512..543 zero the 3x[32][2][512] shadow stats; block 512 zeroes ctr.
__global__ __launch_bounds__(256) void prepk(
    const float* __restrict__ x, u16* __restrict__ xT,
    float* __restrict__ stats, int* __restrict__ ctr) {
    const int tid = threadIdx.x, bid = blockIdx.x;
    if (bid >= 512) {
        const int z0 = (bid - 512) * 3072;
        for (int i = tid; i < 3072; i += 256) stats[z0 + i] = 0.f;
        if (bid == 512 && tid < 8) ctr[tid] = 0;
        return;
    }
    __shared__ float T[64][65];
    const int f0 = (bid & 63) * 64, b0 = (bid >> 6) * 64;
    const int r = tid >> 4, c4 = (tid & 15) * 4;
#pragma unroll
    for (int rr = 0; rr < 4; ++rr) {
        const int row = r + rr * 16;
        const float4 v = *(const float4*)(x + (size_t)(b0 + row) * 4096 + f0 + c4);
        T[row][c4] = v.x; T[row][c4 + 1] = v.y;
        T[row][c4 + 2] = v.z; T[row][c4 + 3] = v.w;
    }
    __syncthreads();
#pragma unroll
    for (int half = 0; half < 2; ++half) {
        const int fr = (tid >> 3) + half * 32;
        const int bq = (tid & 7) * 8;
        uint4 pk;
        pk.x = (u32)f2bf(T[bq + 0][fr]) | ((u32)f2bf(T[bq + 1][fr]) << 16);
        pk.y = (u32)f2bf(T[bq + 2][fr]) | ((u32)f2bf(T[bq + 3][fr]) << 16);
        pk.z = (u32)f2bf(T[bq + 4][fr]) | ((u32)f2bf(T[bq + 5][fr]) << 16);
        pk.w = (u32)f2bf(T[bq + 6][fr]) | ((u32)f2bf(T[bq + 7][fr]) << 16);
        *(uint4*)(xT + (size_t)(f0 + fr) * 512 + b0 + bq) = pk;
    }
}

// ---------------------------------------------------------------------------
__device__ __forceinline__ void gridbar(int* c) {
    __threadfence();                 // release: drain this block's stores
    __syncthreads();
    if (threadIdx.x == 0) {
        __hip_atomic_fetch_add(c, 1, __ATOMIC_RELEASE, __HIP_MEMORY_SCOPE_AGENT);
        while (__hip_atomic_load(c, __ATOMIC_RELAXED, __HIP_MEMORY_SCOPE_AGENT) < NBLK)
            __builtin_amdgcn_s_sleep(2);
    }
    __syncthreads();
    __threadfence();                 // acquire: invalidate stale cached lines
}

// block-local fold of NSH shadow stats -> mr2[col] = {mean, rstd}
__device__ __forceinline__ void foldstats(const float* __restrict__ gsb,
                                          float invM, float2* mr2) {
    const int t = threadIdx.x;
    if (t < 512) {
        float s = 0.f, q = 0.f;
#pragma unroll
        for (int sh = 0; sh < NSH; ++sh) {
            s += gsb[sh * 1024 + t];
            q += gsb[sh * 1024 + 512 + t];
        }
        const float m = s * invM;
        mr2[t] = make_float2(m, rsqrtf(q * invM - m * m + EPS));
    }
    __syncthreads();
}

// ---------------------------------------------------------------------------
__global__ __launch_bounds__(512, 4) void fused(
    const u16* __restrict__ xT, const float* __restrict__ weight,
    const int* __restrict__ edge_src, const float* __restrict__ bias,
    const float* __restrict__ lng, const float* __restrict__ lnb,
    u16* __restrict__ act1, u16* __restrict__ act2, u16* __restrict__ act3,
    float* __restrict__ stats, int* __restrict__ ctr,
    float* __restrict__ out) {
    __shared__ int2 eE[8][FAN_IN];   // per-wave staged edge list (8 KB)
    __shared__ float2 mr2[512];      // folded per-column {mean, rstd} (4 KB)
    const int tid = threadIdx.x;
    const int w8 = tid >> 6, lane = tid & 63;
    const int gw = blockIdx.x * 8 + w8;          // global wave id [0,2048)
    const int shadow = (gw & (NSH - 1)) * 1024;
    float a[8];

    // ================= P1: layer-1 gather, node = gw, 8 cols/lane ==========
    {
        const int eb = gw * FAN_IN;
        const int2 s2 = *(const int2*)(edge_src + eb + lane * 2);
        const float2 w2 = *(const float2*)(weight + eb + lane * 2);
        int4 ent; ent.x = s2.x << 10; ent.y = __float_as_int(w2.x);
        ent.z = s2.y << 10; ent.w = __float_as_int(w2.y);
        *(int4*)&eE[w8][lane * 2] = ent;
#pragma unroll
        for (int j = 0; j < 8; ++j) a[j] = 0.f;
        const u32 vb = (u32)(lane * 16);
#pragma unroll 8
        for (int k = 0; k < FAN_IN; ++k) {
            const int2 e = eE[w8][k];
            const uint4 v = *(const uint4*)((const char*)xT + ((u32)e.x + vb));
            const float wv = __int_as_float(e.y);
            a[0] = fmaf(wv, bflo(v.x), a[0]); a[1] = fmaf(wv, bfhi(v.x), a[1]);
            a[2] = fmaf(wv, bflo(v.y), a[2]); a[3] = fmaf(wv, bfhi(v.y), a[3]);
            a[4] = fmaf(wv, bflo(v.z), a[4]); a[5] = fmaf(wv, bfhi(v.z), a[5]);
            a[6] = fmaf(wv, bflo(v.w), a[6]); a[7] = fmaf(wv, bfhi(v.w), a[7]);
        }
        const float bv = bias[gw];
        float* gs = stats + shadow;
#pragma unroll
        for (int j = 0; j < 8; ++j) {
            a[j] += bv;
            atomicAdd(&gs[lane * 8 + j], a[j]);
            atomicAdd(&gs[512 + lane * 8 + j], a[j] * a[j]);
        }
    }
    gridbar(&ctr[0]);
    foldstats(stats, 1.f / 2048.f, mr2);
    {   // normalize own row (LN over nodes, per column) + ReLU -> act1 bf16
        const float gg = lng[gw], bb = lnb[gw];
        u32 pk[4];
#pragma unroll
        for (int j = 0; j < 4; ++j) {
            const float2 ma = mr2[lane * 8 + 2 * j];
            const float2 mb = mr2[lane * 8 + 2 * j + 1];
            const float x0 = fmaxf(fmaf(gg * (a[2 * j] - ma.x), ma.y, bb), 0.f);
            const float x1 = fmaxf(fmaf(gg * (a[2 * j + 1] - mb.x), mb.y, bb), 0.f);
            pk[j] = (u32)f2bf(x0) | ((u32)f2bf(x1) << 16);
        }
        *(uint4*)((char*)act1 + gw * 1024 + lane * 16) = *(const uint4*)pk;
    }
    gridbar(&ctr[1]);

    // ============ P2: layer-2 gather, node = gw>>1, half = gw&1 ============
    {
        const int node = gw >> 1, half = gw & 1;
        const int eb = 262144 + node * FAN_IN;
        const int2 s2 = *(const int2*)(edge_src + eb + lane * 2);
        const float2 w2 = *(const float2*)(weight + eb + lane * 2);
        int4 ent; ent.x = (s2.x - 4096) << 10; ent.y = __float_as_int(w2.x);
        ent.z = (s2.y - 4096) << 10; ent.w = __float_as_int(w2.y);
        *(int4*)&eE[w8][lane * 2] = ent;
        float b4[4] = {0.f, 0.f, 0.f, 0.f};
        const u32 vb = (u32)(half * 512 + lane * 8);
#pragma unroll 8
        for (int k = 0; k < FAN_IN; ++k) {
            const int2 e = eE[w8][k];
            const uint2 v = *(const uint2*)((const char*)act1 + ((u32)e.x + vb));
            const float wv = __int_as_float(e.y);
            b4[0] = fmaf(wv, bflo(v.x), b4[0]); b4[1] = fmaf(wv, bfhi(v.x), b4[1]);
            b4[2] = fmaf(wv, bflo(v.y), b4[2]); b4[3] = fmaf(wv, bfhi(v.y), b4[3]);
        }
        const float bv = bias[2048 + node];
        float* gs = stats + NSH * 1024 + shadow;
        const int c0 = half * 256 + lane * 4;
#pragma unroll
        for (int j = 0; j < 4; ++j) {
            b4[j] += bv;
            atomicAdd(&gs[c0 + j], b4[j]);
            atomicAdd(&gs[512 + c0 + j], b4[j] * b4[j]);
            a[j] = b4[j];
        }
    }
    gridbar(&ctr[2]);
    foldstats(stats + NSH * 1024, 1.f / 1024.f, mr2);
    {
        const int node = gw >> 1, half = gw & 1;
        const float gg = lng[2048 + node], bb = lnb[2048 + node];
        const int c0 = half * 256 + lane * 4;
        u32 pk[2];
#pragma unroll
        for (int j = 0; j < 2; ++j) {
            const float2 ma = mr2[c0 + 2 * j];
            const float2 mb = mr2[c0 + 2 * j + 1];
            const float x0 = fmaxf(fmaf(gg * (a[2 * j] - ma.x), ma.y, bb), 0.f);
            const float x1 = fmaxf(fmaf(gg * (a[2 * j + 1] - mb.x), mb.y, bb), 0.f);
            pk[j] = (u32)f2bf(x0) | ((u32)f2bf(x1) << 16);
        }
        *(uint2*)((char*)act2 + node * 1024 + half * 512 + lane * 8) =
            *(const uint2*)pk;
    }
    gridbar(&ctr[3]);

    // ============ P3: layer-3 gather, node = gw>>2, q = gw&3 ===============
    {
        const int node = gw >> 2, q = gw & 3;
        const int eb = 393216 + node * FAN_IN;
        const int2 s2 = *(const int2*)(edge_src + eb + lane * 2);
        const float2 w2 = *(const float2*)(weight + eb + lane * 2);
        int4 ent; ent.x = (s2.x - 6144) << 10; ent.y = __float_as_int(w2.x);
        ent.z = (s2.y - 6144) << 10; ent.w = __float_as_int(w2.y);
        *(int4*)&eE[w8][lane * 2] = ent;
        float c2[2] = {0.f, 0.f};
        const u32 vb = (u32)(q * 256 + lane * 4);
#pragma unroll 8
        for (int k = 0; k < FAN_IN; ++k) {
            const int2 e = eE[w8][k];
            const u32 v = *(const u32*)((const char*)act2 + ((u32)e.x + vb));
            const float wv = __int_as_float(e.y);
            c2[0] = fmaf(wv, bflo(v), c2[0]);
            c2[1] = fmaf(wv, bfhi(v), c2[1]);
        }
        const float bv = bias[3072 + node];
        float* gs = stats + 2 * NSH * 1024 + shadow;
        const int c0 = q * 128 + lane * 2;
#pragma unroll
        for (int j = 0; j < 2; ++j) {
            c2[j] += bv;
            atomicAdd(&gs[c0 + j], c2[j]);
            atomicAdd(&gs[512 + c0 + j], c2[j] * c2[j]);
            a[j] = c2[j];
        }
    }
    gridbar(&ctr[4]);
    foldstats(stats + 2 * NSH * 1024, 1.f / 512.f, mr2);
    {
        const int node = gw >> 2, q = gw & 3;
        const float gg = lng[3072 + node], bb = lnb[3072 + node];
        const int c0 = q * 128 + lane * 2;
        const float2 ma = mr2[c0], mb = mr2[c0 + 1];
        const float x0 = fmaxf(fmaf(gg * (a[0] - ma.x), ma.y, bb), 0.f);
        const float x1 = fmaxf(fmaf(gg * (a[1] - mb.x), mb.y, bb), 0.f);
        const u32 pk = (u32)f2bf(x0) | ((u32)f2bf(x1) << 16);
        *(u32*)((char*)act3 + node * 1024 + q * 256 + lane * 4) = pk;
    }
    gridbar(&ctr[5]);

    // ============ P4: output layer (blocks 0..3 only) ======================
    if (blockIdx.x < 4) {
        int2* eF = (int2*)eE;
        if (tid < 256) {
            const int s = edge_src[458752 + tid] - 7168;
            int2 e; e.x = s << 10; e.y = __float_as_int(weight[458752 + tid]);
            eF[tid] = e;
        }
        __syncthreads();
        if (tid < 256) {
            const int tgt = tid >> 7;
            const int col = blockIdx.x * 128 + (tid & 127);
            float acc = 0.f;
#pragma unroll 8
            for (int k = 0; k < FAN_IN; ++k) {
                const int2 e = eF[tgt * FAN_IN + k];
                const u16 v = *(const u16*)((const char*)act3 + ((u32)e.x + (u32)(col * 2)));
                acc = fmaf(__int_as_float(e.y), bflo((u32)v << 16 >> 16), acc);
            }
            out[(size_t)col * 2 + tgt] = acc + bias[3584 + tgt];
        }
    }
}

// ---------------------------------------------------------------------------
extern "C" void kernel_launch(void* const* d_in, const int* in_sizes, int n_in,
                              void* d_out, int out_size, void* d_ws, size_t ws_size,
                              hipStream_t stream) {
    const float* x        = (const float*)d_in[0];
    const float* weight   = (const float*)d_in[1];
    const float* bias     = (const float*)d_in[2];
    const float* ln_gamma = (const float*)d_in[3];
    const float* ln_beta  = (const float*)d_in[4];
    const int*   edge_src = (const int*)d_in[5];
    float* out = (float*)d_out;

    u16* xT   = (u16*)d_ws;                          // [4096][512] bf16 4 MB
    u16* act1 = xT + (size_t)4096 * 512;             // [2048][512] bf16 2 MB
    u16* act2 = act1 + (size_t)2048 * 512;           // [1024][512] bf16 1 MB
    u16* act3 = act2 + (size_t)1024 * 512;           // [512][512] bf16 .5 MB
    float* stats = (float*)(act3 + (size_t)512 * 512); // 3 x [32][2][512]
    int* ctr = (int*)(stats + 3 * NSH * 1024);       // 8 barrier counters

    prepk<<<544, 256, 0, stream>>>(x, xT, stats, ctr);
    fused<<<NBLK, 512, 0, stream>>>(
        xT, weight, edge_src, bias, ln_gamma, ln_beta,
        act1, act2, act3, stats, ctr, out);
}

// Round 5
// 591.627 us; speedup vs baseline: 1.1018x; 1.1018x over previous
//
#include <hip/hip_runtime.h>

// LAYER_IDX = [0, 4096, 6144, 7168, 7680, 7682]
// L1: 4096->2048 ebase 0       | L2: 2048->1024 ebase 262144
// L3: 1024->512  ebase 393216  | out: 512->2    ebase 458752
// v5: persistent kernel, ATOMIC-FREE LN stats (plain per-block partials +
// dedicated 2-col fold stage), LN fused into consumer gathers, XCD-local
// batch halves. Only global atomics left: 6 barrier arrivals (256 each).
#define FAN_IN 128
#define EPS 1e-5f
#define NBLK 256

typedef unsigned short u16;
typedef unsigned int u32;

__device__ __forceinline__ u16 f2bf(float f) {   // fp32->bf16 RNE
    union { float f; u32 u; } v; v.f = f;
    u32 r = v.u + 0x7fffu + ((v.u >> 16) & 1u);
    return (u16)(r >> 16);
}
__device__ __forceinline__ float bflo(u32 u) { return __uint_as_float(u << 16); }
__device__ __forceinline__ float bfhi(u32 u) { return __uint_as_float(u & 0xffff0000u); }

// ---------------------------------------------------------------------------
// prep: transpose x[512][4096] f32 -> xT[4096][512] bf16 (blocks 0..511);
// block 512 zeroes barrier counters.
__global__ __launch_bounds__(256) void prepk(
    const float* __restrict__ x, u16* __restrict__ xT, int* __restrict__ ctr) {
    const int tid = threadIdx.x, bid = blockIdx.x;
    if (bid >= 512) {
        if (tid < 256) ctr[tid] = 0;
        return;
    }
    __shared__ float T[64][65];
    const int f0 = (bid & 63) * 64, b0 = (bid >> 6) * 64;
    const int r = tid >> 4, c4 = (tid & 15) * 4;
#pragma unroll
    for (int rr = 0; rr < 4; ++rr) {
        const int row = r + rr * 16;
        const float4 v = *(const float4*)(x + (size_t)(b0 + row) * 4096 + f0 + c4);
        T[row][c4] = v.x; T[row][c4 + 1] = v.y;
        T[row][c4 + 2] = v.z; T[row][c4 + 3] = v.w;
    }
    __syncthreads();
#pragma unroll
    for (int half = 0; half < 2; ++half) {
        const int fr = (tid >> 3) + half * 32;
        const int bq = (tid & 7) * 8;
        uint4 pk;
        pk.x = (u32)f2bf(T[bq + 0][fr]) | ((u32)f2bf(T[bq + 1][fr]) << 16);
        pk.y = (u32)f2bf(T[bq + 2][fr]) | ((u32)f2bf(T[bq + 3][fr]) << 16);
        pk.z = (u32)f2bf(T[bq + 4][fr]) | ((u32)f2bf(T[bq + 5][fr]) << 16);
        pk.w = (u32)f2bf(T[bq + 6][fr]) | ((u32)f2bf(T[bq + 7][fr]) << 16);
        *(uint4*)(xT + (size_t)(f0 + fr) * 512 + b0 + bq) = pk;
    }
}

// ---------------------------------------------------------------------------
__device__ __forceinline__ void gridbar(int* c) {
    __threadfence();
    __syncthreads();
    if (threadIdx.x == 0) {
        __hip_atomic_fetch_add(c, 1, __ATOMIC_RELEASE, __HIP_MEMORY_SCOPE_AGENT);
        while (__hip_atomic_load(c, __ATOMIC_RELAXED, __HIP_MEMORY_SCOPE_AGENT) < NBLK)
            __builtin_amdgcn_s_sleep(2);
    }
    __syncthreads();
    __threadfence();
}

// fold stage: this block reduces cols {2*bid, 2*bid+1} over 256 partials.
__device__ __forceinline__ void fold2(const float* __restrict__ pG,
                                      float2* __restrict__ mr, float invM,
                                      float* red) {
    const int tid = threadIdx.x;
    const int col = blockIdx.x * 2 + (tid >> 8);
    const int prow = tid & 255;
    float s = pG[prow * 1024 + col];
    float q = pG[prow * 1024 + 512 + col];
#pragma unroll
    for (int o = 32; o; o >>= 1) { s += __shfl_down(s, o); q += __shfl_down(q, o); }
    const int w8 = tid >> 6, lane = tid & 63;
    if (lane == 0) { red[w8 * 2] = s; red[w8 * 2 + 1] = q; }
    __syncthreads();
    if ((tid & 255) == 0) {
        const int base = (tid >> 8) * 8;
        const float S = red[base] + red[base + 2] + red[base + 4] + red[base + 6];
        const float Q = red[base + 1] + red[base + 3] + red[base + 5] + red[base + 7];
        const float m = S * invM;
        mr[col] = make_float2(m, rsqrtf(Q * invM - m * m + EPS));
    }
    __syncthreads();
}

// ---------------------------------------------------------------------------
__global__ __launch_bounds__(512, 2) void fused(
    const u16* __restrict__ xT, const float* __restrict__ weight,
    const int* __restrict__ edge_src, const float* __restrict__ bias,
    const float* __restrict__ lng, const float* __restrict__ lnb,
    u16* __restrict__ raw1, u16* __restrict__ raw2, u16* __restrict__ raw3,
    float* __restrict__ pG, float2* __restrict__ mr1, float2* __restrict__ mr2g,
    float2* __restrict__ mr3, int* __restrict__ ctr, float* __restrict__ out) {
    __shared__ int4 eE[8][128];          // 16 KB staged edge lists
    __shared__ float cs[512], cq[512];   // 4 KB block stats partials
    __shared__ float red[16];
    const int tid = threadIdx.x, bid = blockIdx.x;
    const int w8 = tid >> 6, lane = tid & 63;
    const int hb = (bid & 7) >> 2;               // batch half (XCD group)
    const int bidx = (bid >> 3) * 4 + (bid & 3); // [0,128) within half-group
    const u32 vb2 = (u32)(hb * 512 + lane * 8);  // byte offset for 4 cols
    const int c0h = hb * 256 + lane * 4;

    // ================= P1: layer-1 gather, 2 nodes/wave, 4 cols/lane =======
    cs[tid] = 0.f; cq[tid] = 0.f;
    __syncthreads();
    for (int rep = 0; rep < 2; ++rep) {
        const int node = bidx * 16 + w8 * 2 + rep;       // [0,2048)
        const int eb = node * FAN_IN;
        const int2 s2 = *(const int2*)(edge_src + eb + lane * 2);
        const float2 w2 = *(const float2*)(weight + eb + lane * 2);
        int4 ent; ent.x = s2.x << 10; ent.y = __float_as_int(w2.x);
        ent.z = s2.y << 10; ent.w = __float_as_int(w2.y);
        eE[w8][lane] = ent;                              // 64 pair-entries
        float a0 = 0.f, a1 = 0.f, a2 = 0.f, a3 = 0.f;
#pragma unroll 8
        for (int k = 0; k < 64; ++k) {
            const int4 e = eE[w8][k];
            const uint2 v0 = *(const uint2*)((const char*)xT + ((u32)e.x + vb2));
            const uint2 v1 = *(const uint2*)((const char*)xT + ((u32)e.z + vb2));
            const float wa = __int_as_float(e.y), wb = __int_as_float(e.w);
            a0 = fmaf(wa, bflo(v0.x), a0); a1 = fmaf(wa, bfhi(v0.x), a1);
            a2 = fmaf(wa, bflo(v0.y), a2); a3 = fmaf(wa, bfhi(v0.y), a3);
            a0 = fmaf(wb, bflo(v1.x), a0); a1 = fmaf(wb, bfhi(v1.x), a1);
            a2 = fmaf(wb, bflo(v1.y), a2); a3 = fmaf(wb, bfhi(v1.y), a3);
        }
        const float bv = bias[node];
        a0 += bv; a1 += bv; a2 += bv; a3 += bv;
        uint2 pk;
        pk.x = (u32)f2bf(a0) | ((u32)f2bf(a1) << 16);
        pk.y = (u32)f2bf(a2) | ((u32)f2bf(a3) << 16);
        *(uint2*)((char*)raw1 + node * 1024 + vb2) = pk;
        atomicAdd(&cs[c0h + 0], a0); atomicAdd(&cq[c0h + 0], a0 * a0);
        atomicAdd(&cs[c0h + 1], a1); atomicAdd(&cq[c0h + 1], a1 * a1);
        atomicAdd(&cs[c0h + 2], a2); atomicAdd(&cq[c0h + 2], a2 * a2);
        atomicAdd(&cs[c0h + 3], a3); atomicAdd(&cq[c0h + 3], a3 * a3);
    }
    __syncthreads();
    pG[bid * 1024 + tid] = cs[tid];
    pG[bid * 1024 + 512 + tid] = cq[tid];
    gridbar(ctr);
    fold2(pG, mr1, 1.f / 2048.f, red);
    gridbar(ctr + 32);

    // ================= P2: layer-2 gather, LN1 inline ======================
    cs[tid] = 0.f; cq[tid] = 0.f;
    __syncthreads();
    {
        const float4 u0 = *(const float4*)((const float*)mr1 + c0h * 2);
        const float4 u1 = *(const float4*)((const float*)mr1 + c0h * 2 + 4);
        const int node = bidx * 8 + w8;                  // [0,1024)
        const int eb = 262144 + node * FAN_IN;
        const int2 s2 = *(const int2*)(edge_src + eb + lane * 2);
        const float2 w2 = *(const float2*)(weight + eb + lane * 2);
        const int ra = s2.x - 4096, rb = s2.y - 4096;
        int4 ea, eb2;
        ea.x = ra << 10; ea.y = __float_as_int(w2.x);
        ea.z = __float_as_int(lng[ra]); ea.w = __float_as_int(lnb[ra]);
        eb2.x = rb << 10; eb2.y = __float_as_int(w2.y);
        eb2.z = __float_as_int(lng[rb]); eb2.w = __float_as_int(lnb[rb]);
        eE[w8][lane * 2] = ea; eE[w8][lane * 2 + 1] = eb2;
        float a0 = 0.f, a1 = 0.f, a2 = 0.f, a3 = 0.f;
#pragma unroll 8
        for (int k = 0; k < FAN_IN; ++k) {
            const int4 e = eE[w8][k];
            const uint2 v = *(const uint2*)((const char*)raw1 + ((u32)e.x + vb2));
            const float w = __int_as_float(e.y);
            const float g = __int_as_float(e.z), bt = __int_as_float(e.w);
            const float x0 = fmaxf(fmaf(g * (bflo(v.x) - u0.x), u0.y, bt), 0.f);
            const float x1 = fmaxf(fmaf(g * (bfhi(v.x) - u0.z), u0.w, bt), 0.f);
            const float x2 = fmaxf(fmaf(g * (bflo(v.y) - u1.x), u1.y, bt), 0.f);
            const float x3 = fmaxf(fmaf(g * (bfhi(v.y) - u1.z), u1.w, bt), 0.f);
            a0 = fmaf(w, x0, a0); a1 = fmaf(w, x1, a1);
            a2 = fmaf(w, x2, a2); a3 = fmaf(w, x3, a3);
        }
        const float bv = bias[2048 + node];
        a0 += bv; a1 += bv; a2 += bv; a3 += bv;
        uint2 pk;
        pk.x = (u32)f2bf(a0) | ((u32)f2bf(a1) << 16);
        pk.y = (u32)f2bf(a2) | ((u32)f2bf(a3) << 16);
        *(uint2*)((char*)raw2 + node * 1024 + vb2) = pk;
        atomicAdd(&cs[c0h + 0], a0); atomicAdd(&cq[c0h + 0], a0 * a0);
        atomicAdd(&cs[c0h + 1], a1); atomicAdd(&cq[c0h + 1], a1 * a1);
        atomicAdd(&cs[c0h + 2], a2); atomicAdd(&cq[c0h + 2], a2 * a2);
        atomicAdd(&cs[c0h + 3], a3); atomicAdd(&cq[c0h + 3], a3 * a3);
    }
    __syncthreads();
    pG[bid * 1024 + tid] = cs[tid];
    pG[bid * 1024 + 512 + tid] = cq[tid];
    gridbar(ctr + 64);
    fold2(pG, mr2g, 1.f / 1024.f, red);
    gridbar(ctr + 96);

    // ================= P3: layer-3 gather, LN2 inline ======================
    cs[tid] = 0.f; cq[tid] = 0.f;
    __syncthreads();
    {
        const int q4 = hb * 2 + (w8 & 1);                // batch quarter
        const u32 vb3 = (u32)(q4 * 256 + lane * 4);
        const int c03 = q4 * 128 + lane * 2;
        const float4 u0 = *(const float4*)((const float*)mr2g + c03 * 2);
        const int node = bidx * 4 + (w8 >> 1);           // [0,512)
        const int eb = 393216 + node * FAN_IN;
        const int2 s2 = *(const int2*)(edge_src + eb + lane * 2);
        const float2 w2 = *(const float2*)(weight + eb + lane * 2);
        const int ra = s2.x - 6144, rb = s2.y - 6144;
        int4 ea, eb2;
        ea.x = ra << 10; ea.y = __float_as_int(w2.x);
        ea.z = __float_as_int(lng[2048 + ra]); ea.w = __float_as_int(lnb[2048 + ra]);
        eb2.x = rb << 10; eb2.y = __float_as_int(w2.y);
        eb2.z = __float_as_int(lng[2048 + rb]); eb2.w = __float_as_int(lnb[2048 + rb]);
        eE[w8][lane * 2] = ea; eE[w8][lane * 2 + 1] = eb2;
        float a0 = 0.f, a1 = 0.f;
#pragma unroll 8
        for (int k = 0; k < FAN_IN; ++k) {
            const int4 e = eE[w8][k];
            const u32 v = *(const u32*)((const char*)raw2 + ((u32)e.x + vb3));
            const float w = __int_as_float(e.y);
            const float g = __int_as_float(e.z), bt = __int_as_float(e.w);
            const float x0 = fmaxf(fmaf(g * (bflo(v) - u0.x), u0.y, bt), 0.f);
            const float x1 = fmaxf(fmaf(g * (bfhi(v) - u0.z), u0.w, bt), 0.f);
            a0 = fmaf(w, x0, a0); a1 = fmaf(w, x1, a1);
        }
        const float bv = bias[3072 + node];
        a0 += bv; a1 += bv;
        const u32 pk = (u32)f2bf(a0) | ((u32)f2bf(a1) << 16);
        *(u32*)((char*)raw3 + node * 1024 + vb3) = pk;
        atomicAdd(&cs[c03 + 0], a0); atomicAdd(&cq[c03 + 0], a0 * a0);
        atomicAdd(&cs[c03 + 1], a1); atomicAdd(&cq[c03 + 1], a1 * a1);
    }
    __syncthreads();
    pG[bid * 1024 + tid] = cs[tid];
    pG[bid * 1024 + 512 + tid] = cq[tid];
    gridbar(ctr + 128);
    fold2(pG, mr3, 1.f / 512.f, red);
    gridbar(ctr + 160);

    // ================= P4: output layer, LN3 inline ========================
    {
        const int col = bid * 2 + (tid >> 8);
        const int sub = tid & 255;
        const int tgt = sub >> 7, k = sub & 127;
        const int es = 458752 + tgt * FAN_IN + k;
        const int s = edge_src[es] - 7168;
        const float w = weight[es];
        const float2 mr = mr3[col];
        const float g = lng[3072 + s], bt = lnb[3072 + s];
        const u16 vh = *(const u16*)((const char*)raw3 + (s << 10) + col * 2);
        const float v = bflo((u32)vh);
        float t = fmaxf(fmaf(g * (v - mr.x), mr.y, bt), 0.f) * w;
#pragma unroll
        for (int o = 32; o; o >>= 1) t += __shfl_down(t, o);
        if (lane == 0) red[w8] = t;
        __syncthreads();
        if ((tid & 127) == 0) {
            const int gidx = tid >> 7;                   // 0..3
            const float r2v = red[gidx * 2] + red[gidx * 2 + 1];
            out[(size_t)(bid * 2 + (gidx >> 1)) * 2 + (gidx & 1)] =
                r2v + bias[3584 + (gidx & 1)];
        }
    }
}

// ---------------------------------------------------------------------------
extern "C" void kernel_launch(void* const* d_in, const int* in_sizes, int n_in,
                              void* d_out, int out_size, void* d_ws, size_t ws_size,
                              hipStream_t stream) {
    const float* x        = (const float*)d_in[0];
    const float* weight   = (const float*)d_in[1];
    const float* bias     = (const float*)d_in[2];
    const float* ln_gamma = (const float*)d_in[3];
    const float* ln_beta  = (const float*)d_in[4];
    const int*   edge_src = (const int*)d_in[5];
    float* out = (float*)d_out;

    u16* xT   = (u16*)d_ws;                              // [4096][512] 4 MB
    u16* raw1 = xT + (size_t)4096 * 512;                 // [2048][512] 2 MB
    u16* raw2 = raw1 + (size_t)2048 * 512;               // [1024][512] 1 MB
    u16* raw3 = raw2 + (size_t)1024 * 512;               // [512][512] .5 MB
    float* pG = (float*)(raw3 + (size_t)512 * 512);      // [256][1024] 1 MB
    float2* mr1 = (float2*)(pG + 256 * 1024);            // [512]
    float2* mr2g = mr1 + 512;                            // [512]
    float2* mr3 = mr2g + 512;                            // [512]
    int* ctr = (int*)(mr3 + 512);                        // 256 ints

    prepk<<<513, 256, 0, stream>>>(x, xT, ctr);
    fused<<<NBLK, 512, 0, stream>>>(
        xT, weight, edge_src, bias, ln_gamma, ln_beta,
        raw1, raw2, raw3, pG, mr1, mr2g, mr3, ctr, out);
}

// Round 6
// 148.436 us; speedup vs baseline: 4.3917x; 3.9858x over previous
//
#include <hip/hip_runtime.h>

// LAYER_IDX = [0, 4096, 6144, 7168, 7680, 7682]
// L1: 4096->2048 ebase 0       | L2: 2048->1024 ebase 262144
// L3: 1024->512  ebase 393216  | out: 512->2    ebase 458752
// v6: multi-kernel (kernel boundaries = device barriers, cheap), ATOMIC-FREE
// LN stats (LDS-reduced per-block partials + tiny fold kernels), LN fused
// into consumer gathers, full-row waves with dwordx4 gather loads.
#define FAN_IN 128
#define EPS 1e-5f

typedef unsigned short u16;
typedef unsigned int u32;

__device__ __forceinline__ u16 f2bf(float f) {   // fp32->bf16 RNE
    union { float f; u32 u; } v; v.f = f;
    u32 r = v.u + 0x7fffu + ((v.u >> 16) & 1u);
    return (u16)(r >> 16);
}
__device__ __forceinline__ float bflo(u32 u) { return __uint_as_float(u << 16); }
__device__ __forceinline__ float bfhi(u32 u) { return __uint_as_float(u & 0xffff0000u); }

// ---------------------------------------------------------------------------
// K0: transpose x[512][4096] f32 -> xT[4096][512] bf16.
__global__ __launch_bounds__(256) void prepk(
    const float* __restrict__ x, u16* __restrict__ xT) {
    const int tid = threadIdx.x, bid = blockIdx.x;
    __shared__ float T[64][65];
    const int f0 = (bid & 63) * 64, b0 = (bid >> 6) * 64;
    const int r = tid >> 4, c4 = (tid & 15) * 4;
#pragma unroll
    for (int rr = 0; rr < 4; ++rr) {
        const int row = r + rr * 16;
        const float4 v = *(const float4*)(x + (size_t)(b0 + row) * 4096 + f0 + c4);
        T[row][c4] = v.x; T[row][c4 + 1] = v.y;
        T[row][c4 + 2] = v.z; T[row][c4 + 3] = v.w;
    }
    __syncthreads();
#pragma unroll
    for (int half = 0; half < 2; ++half) {
        const int fr = (tid >> 3) + half * 32;
        const int bq = (tid & 7) * 8;
        uint4 pk;
        pk.x = (u32)f2bf(T[bq + 0][fr]) | ((u32)f2bf(T[bq + 1][fr]) << 16);
        pk.y = (u32)f2bf(T[bq + 2][fr]) | ((u32)f2bf(T[bq + 3][fr]) << 16);
        pk.z = (u32)f2bf(T[bq + 4][fr]) | ((u32)f2bf(T[bq + 5][fr]) << 16);
        pk.w = (u32)f2bf(T[bq + 6][fr]) | ((u32)f2bf(T[bq + 7][fr]) << 16);
        *(uint4*)(xT + (size_t)(f0 + fr) * 512 + b0 + bq) = pk;
    }
}

// ---------------------------------------------------------------------------
// K1: layer-1 gather. Wave = one node's full 512-col row (8 cols/lane,
// dwordx4 loads). Block = 4 nodes. 512 blocks. Stats: LDS fold over the
// block's 4 waves -> plain-store partials pG1[bid][1024]. No atomics.
__global__ __launch_bounds__(256) void g1(
    const u16* __restrict__ xT, const float* __restrict__ weight,
    const int* __restrict__ edge_src, const float* __restrict__ bias,
    u16* __restrict__ raw1, float* __restrict__ pG1) {
    __shared__ int2 eE[4][FAN_IN];       // 4 KB
    __shared__ float cs[4][512];         // 8 KB
    __shared__ float cq[4][512];         // 8 KB
    const int tid = threadIdx.x, bid = blockIdx.x;
    const int w4 = tid >> 6, lane = tid & 63;
    const int node = bid * 4 + w4;       // [0,2048)
    const int eb = node * FAN_IN;
    {
        const int2 s2 = *(const int2*)(edge_src + eb + lane * 2);
        const float2 w2 = *(const float2*)(weight + eb + lane * 2);
        int4 ent;
        ent.x = s2.x << 10; ent.y = __float_as_int(w2.x);
        ent.z = s2.y << 10; ent.w = __float_as_int(w2.y);
        *(int4*)&eE[w4][lane * 2] = ent;
    }
    float a[8] = {0.f, 0.f, 0.f, 0.f, 0.f, 0.f, 0.f, 0.f};
    const char* xb = (const char*)xT + lane * 16;
#pragma unroll 16
    for (int k = 0; k < FAN_IN; ++k) {
        const int2 e = eE[w4][k];
        const uint4 v = *(const uint4*)(xb + (u32)e.x);
        const float w = __int_as_float(e.y);
        a[0] = fmaf(w, bflo(v.x), a[0]); a[1] = fmaf(w, bfhi(v.x), a[1]);
        a[2] = fmaf(w, bflo(v.y), a[2]); a[3] = fmaf(w, bfhi(v.y), a[3]);
        a[4] = fmaf(w, bflo(v.z), a[4]); a[5] = fmaf(w, bfhi(v.z), a[5]);
        a[6] = fmaf(w, bflo(v.w), a[6]); a[7] = fmaf(w, bfhi(v.w), a[7]);
    }
    const float bv = bias[node];
    u32 pk[4];
#pragma unroll
    for (int j = 0; j < 4; ++j) {
        a[2 * j] += bv; a[2 * j + 1] += bv;
        pk[j] = (u32)f2bf(a[2 * j]) | ((u32)f2bf(a[2 * j + 1]) << 16);
    }
    *(uint4*)((char*)raw1 + node * 1024 + lane * 16) = *(const uint4*)pk;
#pragma unroll
    for (int j = 0; j < 8; ++j) {
        cs[w4][lane * 8 + j] = a[j];
        cq[w4][lane * 8 + j] = a[j] * a[j];
    }
    __syncthreads();
    for (int c = tid; c < 512; c += 256) {
        pG1[bid * 1024 + c] = cs[0][c] + cs[1][c] + cs[2][c] + cs[3][c];
        pG1[bid * 1024 + 512 + c] = cq[0][c] + cq[1][c] + cq[2][c] + cq[3][c];
    }
}

// ---------------------------------------------------------------------------
// fold: block b reduces cols {2b,2b+1} over NP partial rows -> mr[col].
__global__ __launch_bounds__(256) void foldk(
    const float* __restrict__ pG, float2* __restrict__ mr, int NP, float invM) {
    __shared__ float red[8];
    const int tid = threadIdx.x, bid = blockIdx.x;
    const int w = tid >> 6, lane = tid & 63;
    const int col = bid * 2 + (tid >> 7), p0 = tid & 127;
    float s = 0.f, q = 0.f;
    for (int i = 0; i < NP; i += 128) {
        s += pG[(p0 + i) * 1024 + col];
        q += pG[(p0 + i) * 1024 + 512 + col];
    }
#pragma unroll
    for (int o = 32; o; o >>= 1) { s += __shfl_down(s, o); q += __shfl_down(q, o); }
    if (lane == 0) { red[w * 2] = s; red[w * 2 + 1] = q; }
    __syncthreads();
    if (tid == 0) {
        const float S = red[0] + red[2], Q = red[1] + red[3];
        const float m = S * invM;
        mr[bid * 2] = make_float2(m, rsqrtf(Q * invM - m * m + EPS));
    }
    if (tid == 128) {
        const float S = red[4] + red[6], Q = red[5] + red[7];
        const float m = S * invM;
        mr[bid * 2 + 1] = make_float2(m, rsqrtf(Q * invM - m * m + EPS));
    }
}

// ---------------------------------------------------------------------------
// K2/K3: fused gather with source-layer LN+ReLU inline. Wave = one target
// node's full row; source rows are bf16 pre-LN (1 KB); per-edge entry
// {byteoff, w, gamma, beta} staged in LDS.
__global__ __launch_bounds__(256) void gF(
    const u16* __restrict__ rawS, const float2* __restrict__ mrS,
    const float* __restrict__ lngS, const float* __restrict__ lnbS,
    const float* __restrict__ weight, const int* __restrict__ edge_src,
    int ebase, int srcbase, const float* __restrict__ biasN,
    u16* __restrict__ rawT, float* __restrict__ pGT) {
    __shared__ int4 eE[4][FAN_IN];       // 8 KB
    __shared__ float cs[4][512];         // 8 KB
    __shared__ float cq[4][512];         // 8 KB
    const int tid = threadIdx.x, bid = blockIdx.x;
    const int w4 = tid >> 6, lane = tid & 63;
    const int node = bid * 4 + w4;
    const int eb = ebase + node * FAN_IN;
    {
        const int2 s2 = *(const int2*)(edge_src + eb + lane * 2);
        const float2 w2 = *(const float2*)(weight + eb + lane * 2);
        const int ra = s2.x - srcbase, rb = s2.y - srcbase;
        int4 e0, e1;
        e0.x = ra << 10; e0.y = __float_as_int(w2.x);
        e0.z = __float_as_int(lngS[ra]); e0.w = __float_as_int(lnbS[ra]);
        e1.x = rb << 10; e1.y = __float_as_int(w2.y);
        e1.z = __float_as_int(lngS[rb]); e1.w = __float_as_int(lnbS[rb]);
        eE[w4][lane * 2] = e0;
        eE[w4][lane * 2 + 1] = e1;
    }
    // per-lane LN constants for its 8 cols: {m,r} interleaved pairs
    const float* mf = (const float*)mrS;
    const float4 u0 = *(const float4*)(mf + lane * 16);
    const float4 u1 = *(const float4*)(mf + lane * 16 + 4);
    const float4 u2 = *(const float4*)(mf + lane * 16 + 8);
    const float4 u3 = *(const float4*)(mf + lane * 16 + 12);
    float a[8] = {0.f, 0.f, 0.f, 0.f, 0.f, 0.f, 0.f, 0.f};
    const char* sbp = (const char*)rawS + lane * 16;
#pragma unroll 8
    for (int k = 0; k < FAN_IN; ++k) {
        const int4 e = eE[w4][k];
        const uint4 v = *(const uint4*)(sbp + (u32)e.x);
        const float w = __int_as_float(e.y);
        const float g = __int_as_float(e.z), bt = __int_as_float(e.w);
        const float x0 = fmaxf(fmaf(g * (bflo(v.x) - u0.x), u0.y, bt), 0.f);
        const float x1 = fmaxf(fmaf(g * (bfhi(v.x) - u0.z), u0.w, bt), 0.f);
        const float x2 = fmaxf(fmaf(g * (bflo(v.y) - u1.x), u1.y, bt), 0.f);
        const float x3 = fmaxf(fmaf(g * (bfhi(v.y) - u1.z), u1.w, bt), 0.f);
        const float x4 = fmaxf(fmaf(g * (bflo(v.z) - u2.x), u2.y, bt), 0.f);
        const float x5 = fmaxf(fmaf(g * (bfhi(v.z) - u2.z), u2.w, bt), 0.f);
        const float x6 = fmaxf(fmaf(g * (bflo(v.w) - u3.x), u3.y, bt), 0.f);
        const float x7 = fmaxf(fmaf(g * (bfhi(v.w) - u3.z), u3.w, bt), 0.f);
        a[0] = fmaf(w, x0, a[0]); a[1] = fmaf(w, x1, a[1]);
        a[2] = fmaf(w, x2, a[2]); a[3] = fmaf(w, x3, a[3]);
        a[4] = fmaf(w, x4, a[4]); a[5] = fmaf(w, x5, a[5]);
        a[6] = fmaf(w, x6, a[6]); a[7] = fmaf(w, x7, a[7]);
    }
    const float bv = biasN[node];
    u32 pk[4];
#pragma unroll
    for (int j = 0; j < 4; ++j) {
        a[2 * j] += bv; a[2 * j + 1] += bv;
        pk[j] = (u32)f2bf(a[2 * j]) | ((u32)f2bf(a[2 * j + 1]) << 16);
    }
    *(uint4*)((char*)rawT + node * 1024 + lane * 16) = *(const uint4*)pk;
#pragma unroll
    for (int j = 0; j < 8; ++j) {
        cs[w4][lane * 8 + j] = a[j];
        cq[w4][lane * 8 + j] = a[j] * a[j];
    }
    __syncthreads();
    for (int c = tid; c < 512; c += 256) {
        pGT[bid * 1024 + c] = cs[0][c] + cs[1][c] + cs[2][c] + cs[3][c];
        pGT[bid * 1024 + 512 + c] = cq[0][c] + cq[1][c] + cq[2][c] + cq[3][c];
    }
}

// ---------------------------------------------------------------------------
// K4: output layer. Block b owns cols {2b,2b+1}: folds layer-3 stats (128
// partials) inline, then 2 targets x 128 edges with LN3+ReLU inline.
__global__ __launch_bounds__(256) void outk(
    const u16* __restrict__ raw3, const float* __restrict__ pG3,
    const float* __restrict__ weight, const int* __restrict__ edge_src,
    const float* __restrict__ lng, const float* __restrict__ lnb,
    const float* __restrict__ bias, float* __restrict__ out) {
    __shared__ float red[8];
    __shared__ float redd[8];
    __shared__ float2 mrL[2];
    const int tid = threadIdx.x, bid = blockIdx.x;
    const int w = tid >> 6, lane = tid & 63;
    {   // fold stats for this block's 2 cols over 128 partials
        const int col = bid * 2 + (tid >> 7), p = tid & 127;
        float s = pG3[p * 1024 + col];
        float q = pG3[p * 1024 + 512 + col];
#pragma unroll
        for (int o = 32; o; o >>= 1) { s += __shfl_down(s, o); q += __shfl_down(q, o); }
        if (lane == 0) { red[w * 2] = s; red[w * 2 + 1] = q; }
    }
    __syncthreads();
    if (tid == 0) {
        const float S = red[0] + red[2], Q = red[1] + red[3];
        const float m = S * (1.f / 512.f);
        mrL[0] = make_float2(m, rsqrtf(Q * (1.f / 512.f) - m * m + EPS));
    }
    if (tid == 128) {
        const float S = red[4] + red[6], Q = red[5] + red[7];
        const float m = S * (1.f / 512.f);
        mrL[1] = make_float2(m, rsqrtf(Q * (1.f / 512.f) - m * m + EPS));
    }
    __syncthreads();
    // per-thread edge (2 targets x 128 edges), evaluated at both cols
    const int es = 458752 + tid;                 // tgt = tid>>7, k = tid&127
    const int s = edge_src[es] - 7168;
    const float wv = weight[es];
    const float g = lng[3072 + s], bt = lnb[3072 + s];
    const char* rb = (const char*)raw3 + ((u32)s << 10);
    float vals[2];
#pragma unroll
    for (int cc = 0; cc < 2; ++cc) {
        const int col = bid * 2 + cc;
        const float2 mr = mrL[cc];
        const u16 vh = *(const u16*)(rb + col * 2);
        const float v = bflo((u32)vh);
        vals[cc] = wv * fmaxf(fmaf(g * (v - mr.x), mr.y, bt), 0.f);
    }
#pragma unroll
    for (int o = 32; o; o >>= 1) {
        vals[0] += __shfl_down(vals[0], o);
        vals[1] += __shfl_down(vals[1], o);
    }
    if (lane == 0) { redd[w * 2] = vals[0]; redd[w * 2 + 1] = vals[1]; }
    __syncthreads();
    if (tid == 0) {
        const float b0 = bias[3584], b1 = bias[3585];
        const int c0 = bid * 2;
        out[(size_t)c0 * 2 + 0] = redd[0] + redd[2] + b0;        // col0 tgt0
        out[(size_t)c0 * 2 + 1] = redd[4] + redd[6] + b1;        // col0 tgt1
        out[(size_t)(c0 + 1) * 2 + 0] = redd[1] + redd[3] + b0;  // col1 tgt0
        out[(size_t)(c0 + 1) * 2 + 1] = redd[5] + redd[7] + b1;  // col1 tgt1
    }
}

// ---------------------------------------------------------------------------
extern "C" void kernel_launch(void* const* d_in, const int* in_sizes, int n_in,
                              void* d_out, int out_size, void* d_ws, size_t ws_size,
                              hipStream_t stream) {
    const float* x        = (const float*)d_in[0];
    const float* weight   = (const float*)d_in[1];
    const float* bias     = (const float*)d_in[2];
    const float* ln_gamma = (const float*)d_in[3];
    const float* ln_beta  = (const float*)d_in[4];
    const int*   edge_src = (const int*)d_in[5];
    float* out = (float*)d_out;

    u16* xT   = (u16*)d_ws;                              // [4096][512] 4 MB
    u16* raw1 = xT + (size_t)4096 * 512;                 // [2048][512] 2 MB
    u16* raw2 = raw1 + (size_t)2048 * 512;               // [1024][512] 1 MB
    u16* raw3 = raw2 + (size_t)1024 * 512;               // [512][512] .5 MB
    float* pG1 = (float*)(raw3 + (size_t)512 * 512);     // [512][1024] 2 MB
    float* pG2 = pG1 + (size_t)512 * 1024;               // [256][1024] 1 MB
    float* pG3 = pG2 + (size_t)256 * 1024;               // [128][1024] .5 MB
    float2* mr1 = (float2*)(pG3 + (size_t)128 * 1024);   // [512]
    float2* mr2 = mr1 + 512;                             // [512]

    prepk<<<512, 256, 0, stream>>>(x, xT);
    g1<<<512, 256, 0, stream>>>(xT, weight, edge_src, bias, raw1, pG1);
    foldk<<<256, 256, 0, stream>>>(pG1, mr1, 512, 1.f / 2048.f);
    gF<<<256, 256, 0, stream>>>(raw1, mr1, ln_gamma, ln_beta, weight, edge_src,
                                262144, 4096, bias + 2048, raw2, pG2);
    foldk<<<256, 256, 0, stream>>>(pG2, mr2, 256, 1.f / 1024.f);
    gF<<<128, 256, 0, stream>>>(raw2, mr2, ln_gamma + 2048, ln_beta + 2048,
                                weight, edge_src, 393216, 6144, bias + 3072,
                                raw3, pG3);
    outk<<<256, 256, 0, stream>>>(raw3, pG3, weight, edge_src,
                                  ln_gamma, ln_beta, bias, out);
}